// Round 1
// baseline (406.059 us; speedup 1.0000x reference)
//
#include <hip/hip_runtime.h>
#include <hip/hip_bf16.h>

#define BB 4
#define NN 1024
#define DIMM 512
#define HH 8
#define DHH 64
#define BN 4096   /* BB*NN */
#define LN_EPS 1e-5f

__device__ inline float wred_sum(float v) {
#pragma unroll
  for (int off = 1; off < 64; off <<= 1) v += __shfl_xor(v, off, 64);
  return v;
}

// ---------------- LN row stats over DIM=512 (q,k,v) --------------------------
__global__ void ln_stats_kernel(const float* __restrict__ q,
                                const float* __restrict__ k,
                                const float* __restrict__ v,
                                float* __restrict__ mean,
                                float* __restrict__ rstd) {
  int wave = threadIdx.x >> 6, lane = threadIdx.x & 63;
  int grow = blockIdx.x * 4 + wave;            // 0..12287
  int tensor = grow >> 12, row = grow & 4095;
  const float* src = tensor == 0 ? q : (tensor == 1 ? k : v);
  const float4* p = (const float4*)(src + (size_t)row * DIMM);
  float4 a = p[lane];
  float4 b = p[lane + 64];
  float s  = a.x + a.y + a.z + a.w + b.x + b.y + b.z + b.w;
  float ss = a.x*a.x + a.y*a.y + a.z*a.z + a.w*a.w
           + b.x*b.x + b.y*b.y + b.z*b.z + b.w*b.w;
  s = wred_sum(s);
  ss = wred_sum(ss);
  if (lane == 0) {
    float m = s * (1.f / DIMM);
    mean[grow] = m;
    rstd[grow] = rsqrtf(ss * (1.f / DIMM) - m * m + LN_EPS);
  }
}

// ---------------- f32 tiled GEMM: C[M,512] = A'[M,512] @ W[512,512]^T --------
// A' = LN(A) when LN==true. Optional bias. M=4096 fixed, K=Nc=512.
template<bool LN, bool BIAS>
__global__ __launch_bounds__(256) void gemm_kernel(
    const float* __restrict__ A, const float* __restrict__ W,
    const float* __restrict__ mean, const float* __restrict__ rstd,
    const float* __restrict__ g, const float* __restrict__ bln,
    const float* __restrict__ bias, float* __restrict__ C) {
  __shared__ float As[16 * 65];
  __shared__ float Bs[16 * 65];
  int tid = threadIdx.x;
  int tx = tid & 15, ty = tid >> 4;
  int tx4 = tx * 4, ty4 = ty * 4;
  int bi = blockIdx.y, bj = blockIdx.x;
  int li = tid >> 2, kv = tid & 3;            // staging: row-in-tile, k-quad
  int arow = bi * 64 + li;
  int brow = bj * 64 + li;
  float m = 0.f, r = 1.f;
  if (LN) { m = mean[arow]; r = rstd[arow]; }
  float acc[4][4] = {};
  for (int ks = 0; ks < DIMM; ks += 16) {
    int kb = ks + kv * 4;
    float4 a = *(const float4*)(A + (size_t)arow * DIMM + kb);
    if (LN) {
      float4 gg = *(const float4*)(g + kb);
      float4 bb = *(const float4*)(bln + kb);
      a.x = (a.x - m) * r * gg.x + bb.x;
      a.y = (a.y - m) * r * gg.y + bb.y;
      a.z = (a.z - m) * r * gg.z + bb.z;
      a.w = (a.w - m) * r * gg.w + bb.w;
    }
    As[(kv*4+0)*65 + li] = a.x;
    As[(kv*4+1)*65 + li] = a.y;
    As[(kv*4+2)*65 + li] = a.z;
    As[(kv*4+3)*65 + li] = a.w;
    float4 w4 = *(const float4*)(W + (size_t)brow * DIMM + kb);
    Bs[(kv*4+0)*65 + li] = w4.x;
    Bs[(kv*4+1)*65 + li] = w4.y;
    Bs[(kv*4+2)*65 + li] = w4.z;
    Bs[(kv*4+3)*65 + li] = w4.w;
    __syncthreads();
#pragma unroll
    for (int kk = 0; kk < 16; ++kk) {
      float av0 = As[kk*65 + ty4 + 0];
      float av1 = As[kk*65 + ty4 + 1];
      float av2 = As[kk*65 + ty4 + 2];
      float av3 = As[kk*65 + ty4 + 3];
      float bv0 = Bs[kk*65 + tx4 + 0];
      float bv1 = Bs[kk*65 + tx4 + 1];
      float bv2 = Bs[kk*65 + tx4 + 2];
      float bv3 = Bs[kk*65 + tx4 + 3];
      acc[0][0] += av0*bv0; acc[0][1] += av0*bv1; acc[0][2] += av0*bv2; acc[0][3] += av0*bv3;
      acc[1][0] += av1*bv0; acc[1][1] += av1*bv1; acc[1][2] += av1*bv2; acc[1][3] += av1*bv3;
      acc[2][0] += av2*bv0; acc[2][1] += av2*bv1; acc[2][2] += av2*bv2; acc[2][3] += av2*bv3;
      acc[3][0] += av3*bv0; acc[3][1] += av3*bv1; acc[3][2] += av3*bv2; acc[3][3] += av3*bv3;
    }
    __syncthreads();
  }
#pragma unroll
  for (int rr = 0; rr < 4; ++rr) {
    int row = bi * 64 + ty4 + rr;
    int col = bj * 64 + tx4;
    float4 o = {acc[rr][0], acc[rr][1], acc[rr][2], acc[rr][3]};
    if (BIAS) {
      float4 bb = *(const float4*)(bias + col);
      o.x += bb.x; o.y += bb.y; o.z += bb.z; o.w += bb.w;
    }
    *(float4*)(C + (size_t)row * DIMM + col) = o;
  }
}

// ---------------- per-(h,b,n) stats over DH=64 for f_q, f_k ------------------
__global__ void row_stats_kernel(const float* __restrict__ fq,
                                 const float* __restrict__ fk,
                                 float* __restrict__ rn, float* __restrict__ mn,
                                 float* __restrict__ vr) {
  int wave = threadIdx.x >> 6, lane = threadIdx.x & 63;
  int gidx = blockIdx.x * 4 + wave;            // 0..65535
  int tensor = gidx >> 15, idx = gidx & 32767;
  int n = idx & 1023, hb = idx >> 10, b = hb & 3, h = hb >> 2;
  const float* f = tensor ? fk : fq;
  float x = f[(size_t)(b * NN + n) * DIMM + h * DHH + lane];
  float s = wred_sum(x);
  float ss = wred_sum(x * x);
  if (lane == 0) {
    rn[gidx] = rsqrtf(ss);                      // 1/||row||
    float mean = s * (1.f / DHH);
    mn[gidx] = mean;
    vr[gidx] = (ss - DHH * mean * mean) * (1.f / (DHH - 1));
  }
}

// ---------------- partial column sums of f_q / f_k (for global means) --------
__global__ void gpart_kernel(const float* __restrict__ fq,
                             const float* __restrict__ fk,
                             float* __restrict__ gp) {
  int tensor = blockIdx.x >> 6, rb = blockIdx.x & 63;
  const float* f = tensor ? fk : fq;
  int t = threadIdx.x;
  float a0 = 0.f, a1 = 0.f;
  for (int rr = 0; rr < 64; ++rr) {
    size_t row = (size_t)(rb * 64 + rr) * DIMM;
    a0 += f[row + t];
    a1 += f[row + t + 256];
  }
  gp[(size_t)(tensor * 64 + rb) * DIMM + t] = a0;
  gp[(size_t)(tensor * 64 + rb) * DIMM + t + 256] = a1;
}

// ---------------- head-weight MLP (one block, deterministic) -----------------
__global__ void mlp_kernel(const float* __restrict__ gp,
                           const float* __restrict__ W1, const float* __restrict__ b1,
                           const float* __restrict__ lg, const float* __restrict__ lb,
                           const float* __restrict__ W2, const float* __restrict__ b2,
                           float* __restrict__ wts) {
  __shared__ float fq[512], fk[512];
  int t = threadIdx.x;
  float sq = 0.f, sk = 0.f;
  for (int p = 0; p < 64; ++p) {
    sq += gp[(size_t)p * 512 + t];
    sk += gp[(size_t)(64 + p) * 512 + t];
  }
  fq[t] = sq * (1.f / BN);
  fk[t] = sk * (1.f / BN);
  __syncthreads();
  int h = t >> 6, j = t & 63;
  float pre = b1[j];
  for (int i = 0; i < 64; ++i) pre += fq[h * 64 + i] * W1[j * 128 + i];
  for (int i = 0; i < 64; ++i) pre += fk[h * 64 + i] * W1[j * 128 + 64 + i];
  float s = wred_sum(pre);
  float ss = wred_sum(pre * pre);
  float mean = s * (1.f / 64.f);
  float var = ss * (1.f / 64.f) - mean * mean;
  float hdn = (pre - mean) * rsqrtf(var + LN_EPS) * lg[j] + lb[j];
  hdn = fmaxf(hdn, 0.f);
  float l0 = wred_sum(hdn * W2[0 * 64 + j]) + b2[0];
  float l1 = wred_sum(hdn * W2[1 * 64 + j]) + b2[1];
  float l2 = wred_sum(hdn * W2[2 * 64 + j]) + b2[2];
  float mx = fmaxf(l0, fmaxf(l1, l2));
  float e0 = __expf(l0 - mx), e1 = __expf(l1 - mx), e2 = __expf(l2 - mx);
  float inv = 1.f / (e0 + e1 + e2);
  if (j == 0) {
    wts[h * 3 + 0] = e0 * inv;
    wts[h * 3 + 1] = e1 * inv;
    wts[h * 3 + 2] = e2 * inv;
  }
}

// ---------------- rank-1 vectors: sum_m kmean[m]*v[m,:], sum_m kvar[m]*v[m,:]
__global__ void rank1_kernel(const float* __restrict__ fv,
                             const float* __restrict__ kmn,
                             const float* __restrict__ kvr,
                             float* __restrict__ kvm, float* __restrict__ kvv) {
  __shared__ float pm[4][64], pv[4][64];
  int hb = blockIdx.x;
  int h = hb >> 2, b = hb & 3;
  int w = threadIdx.x >> 6, d = threadIdx.x & 63;
  float am = 0.f, av = 0.f;
  for (int mm = 0; mm < 256; ++mm) {
    int m = w * 256 + mm;
    float vv = fv[(size_t)(b * NN + m) * DIMM + h * DHH + d];
    am += kmn[hb * 1024 + m] * vv;
    av += kvr[hb * 1024 + m] * vv;
  }
  pm[w][d] = am;
  pv[w][d] = av;
  __syncthreads();
  if (threadIdx.x < 64) {
    kvm[hb * 64 + d] = pm[0][d] + pm[1][d] + pm[2][d] + pm[3][d];
    kvv[hb * 64 + d] = pv[0][d] + pv[1][d] + pv[2][d] + pv[3][d];
  }
}

// ---------------- tiled mixed-attention: out = mixed @ f_v -------------------
__global__ __launch_bounds__(256) void attn_kernel(
    const float* __restrict__ fq, const float* __restrict__ fk,
    const float* __restrict__ fv, const float* __restrict__ rn,
    const float* __restrict__ mn, const float* __restrict__ vr,
    const float* __restrict__ wts, const float* __restrict__ kvm,
    const float* __restrict__ kvv, float* __restrict__ out) {
  __shared__ float Qs[64 * 65];
  __shared__ float Ks[64 * 65];
  __shared__ float Vs[64 * 64];
  __shared__ float Ss[64 * 68];
  __shared__ float qrn[64], qmn_s[64], qvr_s[64], krn[64];
  int qt = blockIdx.x, b = blockIdx.y, h = blockIdx.z;
  int hb = h * 4 + b;
  int tid = threadIdx.x, tx = tid & 15, ty = tid >> 4;
  int tx4 = tx * 4, ty4 = ty * 4;
  float w0 = wts[h * 3 + 0], w1 = wts[h * 3 + 1], w2 = wts[h * 3 + 2];
  int n0 = qt * 64;
  int kvec = tid & 15, i0 = tid >> 4;
  // load Q tile transposed: Qs[d][n]
#pragma unroll
  for (int rep = 0; rep < 4; ++rep) {
    int i = i0 + rep * 16;
    float4 a = *(const float4*)(fq + (size_t)(b * NN + n0 + i) * DIMM + h * DHH + kvec * 4);
    Qs[(kvec*4+0)*65 + i] = a.x;
    Qs[(kvec*4+1)*65 + i] = a.y;
    Qs[(kvec*4+2)*65 + i] = a.z;
    Qs[(kvec*4+3)*65 + i] = a.w;
  }
  if (tid < 64) {
    qrn[tid]   = rn[hb * 1024 + n0 + tid] * w0;      // fold w0 into 1/qn
    qmn_s[tid] = mn[hb * 1024 + n0 + tid];
    qvr_s[tid] = vr[hb * 1024 + n0 + tid];
  }
  float acc[4][4] = {};
  const float f1 = w1 * (1.f / 64.f);
  for (int kt = 0; kt < 16; ++kt) {
    int m0 = kt * 64;
    // load K transposed, V direct
#pragma unroll
    for (int rep = 0; rep < 4; ++rep) {
      int i = i0 + rep * 16;
      float4 a = *(const float4*)(fk + (size_t)(b * NN + m0 + i) * DIMM + h * DHH + kvec * 4);
      Ks[(kvec*4+0)*65 + i] = a.x;
      Ks[(kvec*4+1)*65 + i] = a.y;
      Ks[(kvec*4+2)*65 + i] = a.z;
      Ks[(kvec*4+3)*65 + i] = a.w;
      float4 vv = *(const float4*)(fv + (size_t)(b * NN + m0 + i) * DIMM + h * DHH + kvec * 4);
      *(float4*)(Vs + i * 64 + kvec * 4) = vv;
    }
    if (tid < 64) krn[tid] = rn[32768 + hb * 1024 + m0 + tid];
    __syncthreads();
    // S = Q @ K^T (64x64x64)
    float s[4][4] = {};
#pragma unroll 8
    for (int d = 0; d < 64; ++d) {
      float q0 = Qs[d*65 + ty4 + 0];
      float q1 = Qs[d*65 + ty4 + 1];
      float q2 = Qs[d*65 + ty4 + 2];
      float q3 = Qs[d*65 + ty4 + 3];
      float k0 = Ks[d*65 + tx4 + 0];
      float k1 = Ks[d*65 + tx4 + 1];
      float k2 = Ks[d*65 + tx4 + 2];
      float k3 = Ks[d*65 + tx4 + 3];
      s[0][0] += q0*k0; s[0][1] += q0*k1; s[0][2] += q0*k2; s[0][3] += q0*k3;
      s[1][0] += q1*k0; s[1][1] += q1*k1; s[1][2] += q1*k2; s[1][3] += q1*k3;
      s[2][0] += q2*k0; s[2][1] += q2*k1; s[2][2] += q2*k2; s[2][3] += q2*k3;
      s[3][0] += q3*k0; s[3][1] += q3*k1; s[3][2] += q3*k2; s[3][3] += q3*k3;
    }
    // transform: mixed = S * (w0/(qn*kn) + w1/64), write to Ss[n][m]
    float rq0 = qrn[ty4+0], rq1 = qrn[ty4+1], rq2 = qrn[ty4+2], rq3 = qrn[ty4+3];
    float rk0 = krn[tx4+0], rk1 = krn[tx4+1], rk2 = krn[tx4+2], rk3 = krn[tx4+3];
    {
      float4 o;
      o.x = s[0][0]*(rq0*rk0 + f1); o.y = s[0][1]*(rq0*rk1 + f1);
      o.z = s[0][2]*(rq0*rk2 + f1); o.w = s[0][3]*(rq0*rk3 + f1);
      *(float4*)(Ss + (ty4+0)*68 + tx4) = o;
      o.x = s[1][0]*(rq1*rk0 + f1); o.y = s[1][1]*(rq1*rk1 + f1);
      o.z = s[1][2]*(rq1*rk2 + f1); o.w = s[1][3]*(rq1*rk3 + f1);
      *(float4*)(Ss + (ty4+1)*68 + tx4) = o;
      o.x = s[2][0]*(rq2*rk0 + f1); o.y = s[2][1]*(rq2*rk1 + f1);
      o.z = s[2][2]*(rq2*rk2 + f1); o.w = s[2][3]*(rq2*rk3 + f1);
      *(float4*)(Ss + (ty4+2)*68 + tx4) = o;
      o.x = s[3][0]*(rq3*rk0 + f1); o.y = s[3][1]*(rq3*rk1 + f1);
      o.z = s[3][2]*(rq3*rk2 + f1); o.w = s[3][3]*(rq3*rk3 + f1);
      *(float4*)(Ss + (ty4+3)*68 + tx4) = o;
    }
    __syncthreads();
    // acc += mixed @ V (64x64x64)
#pragma unroll 8
    for (int m = 0; m < 64; ++m) {
      float s0 = Ss[(ty4+0)*68 + m];
      float s1 = Ss[(ty4+1)*68 + m];
      float s2 = Ss[(ty4+2)*68 + m];
      float s3 = Ss[(ty4+3)*68 + m];
      float4 vv = *(const float4*)(Vs + m * 64 + tx4);
      acc[0][0] += s0*vv.x; acc[0][1] += s0*vv.y; acc[0][2] += s0*vv.z; acc[0][3] += s0*vv.w;
      acc[1][0] += s1*vv.x; acc[1][1] += s1*vv.y; acc[1][2] += s1*vv.z; acc[1][3] += s1*vv.w;
      acc[2][0] += s2*vv.x; acc[2][1] += s2*vv.y; acc[2][2] += s2*vv.z; acc[2][3] += s2*vv.w;
      acc[3][0] += s3*vv.x; acc[3][1] += s3*vv.y; acc[3][2] += s3*vv.z; acc[3][3] += s3*vv.w;
    }
    __syncthreads();
  }
  // epilogue: rank-1 corrections + store
  float4 km = *(const float4*)(kvm + hb * 64 + tx4);
  float4 kv2 = *(const float4*)(kvv + hb * 64 + tx4);
  const float w264 = w2 * (1.f / 64.f);
#pragma unroll
  for (int rr = 0; rr < 4; ++rr) {
    float qm = qmn_s[ty4 + rr] * w1;
    float qv2 = qvr_s[ty4 + rr] * w264;
    float4 o;
    o.x = acc[rr][0] - qm * km.x + qv2 * kv2.x;
    o.y = acc[rr][1] - qm * km.y + qv2 * kv2.y;
    o.z = acc[rr][2] - qm * km.z + qv2 * kv2.z;
    o.w = acc[rr][3] - qm * km.w + qv2 * kv2.w;
    *(float4*)(out + (size_t)(b * NN + n0 + ty4 + rr) * DIMM + h * DHH + tx4) = o;
  }
}

extern "C" void kernel_launch(void* const* d_in, const int* in_sizes, int n_in,
                              void* d_out, int out_size, void* d_ws, size_t ws_size,
                              hipStream_t stream) {
  const float* q     = (const float*)d_in[0];
  const float* k     = (const float*)d_in[1];
  const float* v     = (const float*)d_in[2];
  const float* ln_g  = (const float*)d_in[3];
  const float* ln_b  = (const float*)d_in[4];
  const float* W_in  = (const float*)d_in[5];
  const float* W_out = (const float*)d_in[6];
  const float* b_out = (const float*)d_in[7];
  const float* wp_W1 = (const float*)d_in[8];
  const float* wp_b1 = (const float*)d_in[9];
  const float* wp_lg = (const float*)d_in[10];
  const float* wp_lb = (const float*)d_in[11];
  const float* wp_W2 = (const float*)d_in[12];
  const float* wp_b2 = (const float*)d_in[13];
  float* out = (float*)d_out;

  float* ws = (float*)d_ws;
  float* f_q     = ws;                  // 2097152
  float* f_k     = ws + 2097152;        // 2097152
  float* f_v     = ws + 4194304;        // 2097152
  float* attn    = ws + 6291456;        // 2097152
  float* ln_mean = ws + 8388608;        // 12288
  float* ln_rstd = ws + 8400896;        // 12288
  float* rn      = ws + 8413184;        // 65536 ([2][32768])
  float* mn      = ws + 8478720;        // 65536
  float* vr      = ws + 8544256;        // 65536
  float* gp      = ws + 8609792;        // 65536
  float* wts     = ws + 8675328;        // 32
  float* kvm     = ws + 8675360;        // 2048
  float* kvv     = ws + 8677408;        // 2048

  ln_stats_kernel<<<3072, 256, 0, stream>>>(q, k, v, ln_mean, ln_rstd);
  gemm_kernel<true, false><<<dim3(8, 64), 256, 0, stream>>>(
      q, W_in, ln_mean, ln_rstd, ln_g, ln_b, nullptr, f_q);
  gemm_kernel<true, false><<<dim3(8, 64), 256, 0, stream>>>(
      k, W_in, ln_mean + 4096, ln_rstd + 4096, ln_g, ln_b, nullptr, f_k);
  gemm_kernel<true, false><<<dim3(8, 64), 256, 0, stream>>>(
      v, W_in, ln_mean + 8192, ln_rstd + 8192, ln_g, ln_b, nullptr, f_v);
  row_stats_kernel<<<16384, 256, 0, stream>>>(f_q, f_k, rn, mn, vr);
  gpart_kernel<<<128, 256, 0, stream>>>(f_q, f_k, gp);
  mlp_kernel<<<1, 512, 0, stream>>>(gp, wp_W1, wp_b1, wp_lg, wp_lb, wp_W2, wp_b2, wts);
  rank1_kernel<<<32, 256, 0, stream>>>(f_v, mn + 32768, vr + 32768, kvm, kvv);
  attn_kernel<<<dim3(16, 4, 8), 256, 0, stream>>>(
      f_q, f_k, f_v, rn, mn, vr, wts, kvm, kvv, attn);
  gemm_kernel<false, true><<<dim3(8, 64), 256, 0, stream>>>(
      attn, W_out, nullptr, nullptr, nullptr, nullptr, b_out, out);
}

// Round 2
// 154.102 us; speedup vs baseline: 2.6350x; 2.6350x over previous
//
#include <hip/hip_runtime.h>
#include <hip/hip_bf16.h>

#define LN_EPS 1e-5f
typedef __attribute__((ext_vector_type(8))) short short8v;
typedef __attribute__((ext_vector_type(4))) float f32x4;
typedef __hip_bfloat16 bf16;

__device__ inline float wred_sum(float v) {
#pragma unroll
  for (int off = 1; off < 64; off <<= 1) v += __shfl_xor(v, off, 64);
  return v;
}

// ---------------- LN row stats over DIM=512 (q,k,v) --------------------------
__global__ void ln_stats_kernel(const float* __restrict__ q,
                                const float* __restrict__ k,
                                const float* __restrict__ v,
                                float* __restrict__ mean,
                                float* __restrict__ rstd) {
  int wave = threadIdx.x >> 6, lane = threadIdx.x & 63;
  int grow = blockIdx.x * 4 + wave;            // 0..12287
  int tensor = grow >> 12, row = grow & 4095;
  const float* src = tensor == 0 ? q : (tensor == 1 ? k : v);
  const float4* p = (const float4*)(src + (size_t)row * 512);
  float4 a = p[lane];
  float4 b = p[lane + 64];
  float s  = a.x + a.y + a.z + a.w + b.x + b.y + b.z + b.w;
  float ss = a.x*a.x + a.y*a.y + a.z*a.z + a.w*a.w
           + b.x*b.x + b.y*b.y + b.z*b.z + b.w*b.w;
  s = wred_sum(s);
  ss = wred_sum(ss);
  if (lane == 0) {
    float m = s * (1.f / 512.f);
    mean[grow] = m;
    rstd[grow] = rsqrtf(ss * (1.f / 512.f) - m * m + LN_EPS);
  }
}

// ---------------- bf16 MFMA GEMM: C[4096,512] = A'[4096,512] @ W[512,512]^T --
// MODE 0: A f32 + fused LN, C bf16.   MODE 1: A bf16, C f32 + bias.
template<int MODE>
__global__ __launch_bounds__(256) void mm_kernel(
    const void* __restrict__ Av, const float* __restrict__ W,
    const float* __restrict__ mean, const float* __restrict__ rstd,
    const float* __restrict__ g, const float* __restrict__ bln,
    const float* __restrict__ bias, void* __restrict__ Cv) {
  __shared__ bf16 As[64 * 72];
  __shared__ bf16 Bs[64 * 72];
  int tid = threadIdx.x;
  int bi = blockIdx.y, bj = blockIdx.x;
  int srow = tid >> 2, kc = (tid & 3) * 16;    // staging: row, k-chunk
  int arow = bi * 64 + srow, brow = bj * 64 + srow;
  int wv = tid >> 6, l = tid & 63;
  int fr = l & 15, fq_ = l >> 4;
  float m = 0.f, r = 1.f;
  if (MODE == 0) { m = mean[arow]; r = rstd[arow]; }
  f32x4 acc[4];
#pragma unroll
  for (int j = 0; j < 4; ++j)
#pragma unroll
    for (int i = 0; i < 4; ++i) acc[j][i] = 0.f;

  for (int ks = 0; ks < 512; ks += 64) {
    if (MODE == 0) {
      const float* A = (const float*)Av;
      bf16 t16[16];
#pragma unroll
      for (int q = 0; q < 4; ++q) {
        float4 a  = *(const float4*)(A + (size_t)arow * 512 + ks + kc + q * 4);
        float4 gg = *(const float4*)(g + ks + kc + q * 4);
        float4 bb = *(const float4*)(bln + ks + kc + q * 4);
        t16[q*4+0] = __float2bfloat16((a.x - m) * r * gg.x + bb.x);
        t16[q*4+1] = __float2bfloat16((a.y - m) * r * gg.y + bb.y);
        t16[q*4+2] = __float2bfloat16((a.z - m) * r * gg.z + bb.z);
        t16[q*4+3] = __float2bfloat16((a.w - m) * r * gg.w + bb.w);
      }
      *(short8v*)&As[srow*72 + kc]     = *(short8v*)&t16[0];
      *(short8v*)&As[srow*72 + kc + 8] = *(short8v*)&t16[8];
    } else {
      const bf16* A = (const bf16*)Av;
      *(short8v*)&As[srow*72 + kc]     = *(const short8v*)(A + (size_t)arow*512 + ks + kc);
      *(short8v*)&As[srow*72 + kc + 8] = *(const short8v*)(A + (size_t)arow*512 + ks + kc + 8);
    }
    {
      bf16 t16[16];
#pragma unroll
      for (int q = 0; q < 4; ++q) {
        float4 w4 = *(const float4*)(W + (size_t)brow * 512 + ks + kc + q * 4);
        t16[q*4+0] = __float2bfloat16(w4.x);
        t16[q*4+1] = __float2bfloat16(w4.y);
        t16[q*4+2] = __float2bfloat16(w4.z);
        t16[q*4+3] = __float2bfloat16(w4.w);
      }
      *(short8v*)&Bs[srow*72 + kc]     = *(short8v*)&t16[0];
      *(short8v*)&Bs[srow*72 + kc + 8] = *(short8v*)&t16[8];
    }
    __syncthreads();
#pragma unroll
    for (int kk = 0; kk < 64; kk += 32) {
      short8v af = *(const short8v*)&As[(wv*16 + fr)*72 + kk + fq_*8];
#pragma unroll
      for (int j = 0; j < 4; ++j) {
        short8v bfr = *(const short8v*)&Bs[(j*16 + fr)*72 + kk + fq_*8];
        acc[j] = __builtin_amdgcn_mfma_f32_16x16x32_bf16(af, bfr, acc[j], 0, 0, 0);
      }
    }
    __syncthreads();
  }
#pragma unroll
  for (int j = 0; j < 4; ++j) {
    int col = bj * 64 + j * 16 + fr;
#pragma unroll
    for (int rr = 0; rr < 4; ++rr) {
      int row = bi * 64 + wv * 16 + fq_ * 4 + rr;
      if (MODE == 0) {
        ((bf16*)Cv)[(size_t)row * 512 + col] = __float2bfloat16(acc[j][rr]);
      } else {
        ((float*)Cv)[(size_t)row * 512 + col] = acc[j][rr] + bias[col];
      }
    }
  }
}

// ---------------- V transpose: f_vt[hb][d][m] <- f_v[(b,m)][h*64+d] ----------
__global__ __launch_bounds__(256) void vtrans_kernel(const bf16* __restrict__ fv,
                                                     bf16* __restrict__ fvt) {
  __shared__ bf16 T[64 * 72];
  int mt = blockIdx.x, hb = blockIdx.y;        // mt 0..15, hb 0..31
  int h = hb >> 2, b = hb & 3;
  int tid = threadIdx.x;
  int mrow = tid >> 2, dc = (tid & 3) * 16;
  const bf16* src = fv + (size_t)(b * 1024 + mt * 64 + mrow) * 512 + h * 64 + dc;
  *(short8v*)&T[mrow*72 + dc]     = *(const short8v*)src;
  *(short8v*)&T[mrow*72 + dc + 8] = *(const short8v*)(src + 8);
  __syncthreads();
  int d = tid >> 2, mc = (tid & 3) * 16;
  bf16 t16[16];
#pragma unroll
  for (int i = 0; i < 16; ++i) t16[i] = T[(mc + i)*72 + d];
  bf16* dst = fvt + (size_t)(hb * 64 + d) * 1024 + mt * 64 + mc;
  *(short8v*)&dst[0] = *(short8v*)&t16[0];
  *(short8v*)&dst[8] = *(short8v*)&t16[8];
}

// ---------------- per-(h,b,n) stats over DH=64 for f_q, f_k ------------------
__global__ void row_stats_kernel(const bf16* __restrict__ fq,
                                 const bf16* __restrict__ fk,
                                 float* __restrict__ rn, float* __restrict__ mn,
                                 float* __restrict__ vr) {
  int wave = threadIdx.x >> 6, lane = threadIdx.x & 63;
  int gidx = blockIdx.x * 4 + wave;            // 0..65535
  int tensor = gidx >> 15, idx = gidx & 32767;
  int n = idx & 1023, hb = idx >> 10, b = hb & 3, h = hb >> 2;
  const bf16* f = tensor ? fk : fq;
  float x = __bfloat162float(f[(size_t)(b * 1024 + n) * 512 + h * 64 + lane]);
  float s = wred_sum(x);
  float ss = wred_sum(x * x);
  if (lane == 0) {
    rn[gidx] = rsqrtf(ss);                      // 1/||row||
    float mean = s * (1.f / 64.f);
    mn[gidx] = mean;
    vr[gidx] = (ss - 64.f * mean * mean) * (1.f / 63.f);
  }
}

// ---------------- partial column sums of f_q / f_k (for global means) --------
__global__ void gpart_kernel(const bf16* __restrict__ fq,
                             const bf16* __restrict__ fk,
                             float* __restrict__ gp) {
  int tensor = blockIdx.x >> 6, rb = blockIdx.x & 63;
  const bf16* f = tensor ? fk : fq;
  int t = threadIdx.x;
  float a0 = 0.f, a1 = 0.f;
  for (int rr = 0; rr < 64; ++rr) {
    size_t row = (size_t)(rb * 64 + rr) * 512;
    a0 += __bfloat162float(f[row + t]);
    a1 += __bfloat162float(f[row + t + 256]);
  }
  gp[(size_t)(tensor * 64 + rb) * 512 + t] = a0;
  gp[(size_t)(tensor * 64 + rb) * 512 + t + 256] = a1;
}

// ---------------- head-weight MLP (one block, deterministic) -----------------
__global__ void mlp_kernel(const float* __restrict__ gp,
                           const float* __restrict__ W1, const float* __restrict__ b1,
                           const float* __restrict__ lg, const float* __restrict__ lb,
                           const float* __restrict__ W2, const float* __restrict__ b2,
                           float* __restrict__ wts) {
  __shared__ float fq[512], fk[512];
  int t = threadIdx.x;
  float sq = 0.f, sk = 0.f;
  for (int p = 0; p < 64; ++p) {
    sq += gp[(size_t)p * 512 + t];
    sk += gp[(size_t)(64 + p) * 512 + t];
  }
  fq[t] = sq * (1.f / 4096.f);
  fk[t] = sk * (1.f / 4096.f);
  __syncthreads();
  int h = t >> 6, j = t & 63;
  float pre = b1[j];
  for (int i = 0; i < 64; ++i) pre += fq[h * 64 + i] * W1[j * 128 + i];
  for (int i = 0; i < 64; ++i) pre += fk[h * 64 + i] * W1[j * 128 + 64 + i];
  float s = wred_sum(pre);
  float ss = wred_sum(pre * pre);
  float mean = s * (1.f / 64.f);
  float var = ss * (1.f / 64.f) - mean * mean;
  float hdn = (pre - mean) * rsqrtf(var + LN_EPS) * lg[j] + lb[j];
  hdn = fmaxf(hdn, 0.f);
  float l0 = wred_sum(hdn * W2[0 * 64 + j]) + b2[0];
  float l1 = wred_sum(hdn * W2[1 * 64 + j]) + b2[1];
  float l2 = wred_sum(hdn * W2[2 * 64 + j]) + b2[2];
  float mx = fmaxf(l0, fmaxf(l1, l2));
  float e0 = __expf(l0 - mx), e1 = __expf(l1 - mx), e2 = __expf(l2 - mx);
  float inv = 1.f / (e0 + e1 + e2);
  if (j == 0) {
    wts[h * 3 + 0] = e0 * inv;
    wts[h * 3 + 1] = e1 * inv;
    wts[h * 3 + 2] = e2 * inv;
  }
}

// ---------------- rank-1 vectors: sum_m kmean[m]*v[m,:], sum_m kvar[m]*v[m,:]
__global__ void rank1_kernel(const bf16* __restrict__ fv,
                             const float* __restrict__ kmn,
                             const float* __restrict__ kvr,
                             float* __restrict__ kvm, float* __restrict__ kvv) {
  __shared__ float pm[4][64], pv[4][64];
  int hb = blockIdx.x;
  int h = hb >> 2, b = hb & 3;
  int w = threadIdx.x >> 6, d = threadIdx.x & 63;
  float am = 0.f, av = 0.f;
  for (int mm = 0; mm < 256; ++mm) {
    int m = w * 256 + mm;
    float vv = __bfloat162float(fv[(size_t)(b * 1024 + m) * 512 + h * 64 + d]);
    am += kmn[hb * 1024 + m] * vv;
    av += kvr[hb * 1024 + m] * vv;
  }
  pm[w][d] = am;
  pv[w][d] = av;
  __syncthreads();
  if (threadIdx.x < 64) {
    kvm[hb * 64 + d] = pm[0][d] + pm[1][d] + pm[2][d] + pm[3][d];
    kvv[hb * 64 + d] = pv[0][d] + pv[1][d] + pv[2][d] + pv[3][d];
  }
}

// ---------------- MFMA mixed-attention: outb = mixed @ f_v (bf16) ------------
__global__ __launch_bounds__(256) void attn_kernel(
    const bf16* __restrict__ fq, const bf16* __restrict__ fk,
    const bf16* __restrict__ fvt, const float* __restrict__ rn,
    const float* __restrict__ mn, const float* __restrict__ vr,
    const float* __restrict__ wts, const float* __restrict__ kvm,
    const float* __restrict__ kvv, bf16* __restrict__ outb) {
  __shared__ bf16 Qs[64 * 72];
  __shared__ bf16 Ks[64 * 72];
  __shared__ bf16 Vt[64 * 72];
  __shared__ bf16 Sb[64 * 72];
  __shared__ float qrn[64], qmn[64], qvr[64], krn[64];
  int qt = blockIdx.x, b = blockIdx.y, h = blockIdx.z;
  int hb = h * 4 + b;
  int tid = threadIdx.x;
  int wv = tid >> 6, l = tid & 63, fr = l & 15, fq_ = l >> 4;
  float w0 = wts[h * 3 + 0], w1 = wts[h * 3 + 1], w2 = wts[h * 3 + 2];
  int n0 = qt * 64;
  int srow = tid >> 2, kc = (tid & 3) * 16;
  // stage Q tile (rows n, cols d) + q stats
  {
    const bf16* qsrc = fq + (size_t)(b * 1024 + n0 + srow) * 512 + h * 64 + kc;
    *(short8v*)&Qs[srow*72 + kc]     = *(const short8v*)qsrc;
    *(short8v*)&Qs[srow*72 + kc + 8] = *(const short8v*)(qsrc + 8);
  }
  if (tid < 64) {
    qrn[tid] = rn[hb * 1024 + n0 + tid] * w0;   // fold w0 into 1/qn
    qmn[tid] = mn[hb * 1024 + n0 + tid];
    qvr[tid] = vr[hb * 1024 + n0 + tid];
  }
  f32x4 acc[4];
#pragma unroll
  for (int j = 0; j < 4; ++j)
#pragma unroll
    for (int i = 0; i < 4; ++i) acc[j][i] = 0.f;
  const float f1 = w1 * (1.f / 64.f);

  for (int kt = 0; kt < 16; ++kt) {
    int m0 = kt * 64;
    __syncthreads();   // prev PV done (and Q staged, first iter)
    {
      const bf16* ksrc = fk + (size_t)(b * 1024 + m0 + srow) * 512 + h * 64 + kc;
      *(short8v*)&Ks[srow*72 + kc]     = *(const short8v*)ksrc;
      *(short8v*)&Ks[srow*72 + kc + 8] = *(const short8v*)(ksrc + 8);
      const bf16* vsrc = fvt + (size_t)(hb * 64 + srow) * 1024 + m0 + kc;
      *(short8v*)&Vt[srow*72 + kc]     = *(const short8v*)vsrc;
      *(short8v*)&Vt[srow*72 + kc + 8] = *(const short8v*)(vsrc + 8);
    }
    if (tid < 64) krn[tid] = rn[32768 + hb * 1024 + m0 + tid];
    __syncthreads();
    // S = Q @ K^T
    f32x4 s[4];
#pragma unroll
    for (int j = 0; j < 4; ++j)
#pragma unroll
      for (int i = 0; i < 4; ++i) s[j][i] = 0.f;
#pragma unroll
    for (int kk = 0; kk < 64; kk += 32) {
      short8v af = *(const short8v*)&Qs[(wv*16 + fr)*72 + kk + fq_*8];
#pragma unroll
      for (int j = 0; j < 4; ++j) {
        short8v bfr = *(const short8v*)&Ks[(j*16 + fr)*72 + kk + fq_*8];
        s[j] = __builtin_amdgcn_mfma_f32_16x16x32_bf16(af, bfr, s[j], 0, 0, 0);
      }
    }
    // mixed = S * (w0/(qn*kn) + w1/64) -> Sb (bf16, row n, col m)
#pragma unroll
    for (int j = 0; j < 4; ++j) {
      int mcol = j * 16 + fr;
      float rk = krn[mcol];
#pragma unroll
      for (int rr = 0; rr < 4; ++rr) {
        int nrow = wv * 16 + fq_ * 4 + rr;
        float val = s[j][rr] * (qrn[nrow] * rk + f1);
        Sb[nrow*72 + mcol] = __float2bfloat16(val);
      }
    }
    __syncthreads();
    // acc += mixed @ V  (A = Sb rows n, k=m; B = Vt rows d, k=m)
#pragma unroll
    for (int kk = 0; kk < 64; kk += 32) {
      short8v af = *(const short8v*)&Sb[(wv*16 + fr)*72 + kk + fq_*8];
#pragma unroll
      for (int j = 0; j < 4; ++j) {
        short8v bfr = *(const short8v*)&Vt[(j*16 + fr)*72 + kk + fq_*8];
        acc[j] = __builtin_amdgcn_mfma_f32_16x16x32_bf16(af, bfr, acc[j], 0, 0, 0);
      }
    }
  }
  // epilogue: rank-1 corrections + bf16 store
  const float w264 = w2 * (1.f / 64.f);
#pragma unroll
  for (int j = 0; j < 4; ++j) {
    int d = j * 16 + fr;
    float km = kvm[hb * 64 + d], kv2 = kvv[hb * 64 + d];
#pragma unroll
    for (int rr = 0; rr < 4; ++rr) {
      int nrow = wv * 16 + fq_ * 4 + rr;
      float o = acc[j][rr] - qmn[nrow] * w1 * km + qvr[nrow] * w264 * kv2;
      outb[(size_t)(b * 1024 + n0 + nrow) * 512 + h * 64 + d] = __float2bfloat16(o);
    }
  }
}

extern "C" void kernel_launch(void* const* d_in, const int* in_sizes, int n_in,
                              void* d_out, int out_size, void* d_ws, size_t ws_size,
                              hipStream_t stream) {
  const float* q     = (const float*)d_in[0];
  const float* k     = (const float*)d_in[1];
  const float* v     = (const float*)d_in[2];
  const float* ln_g  = (const float*)d_in[3];
  const float* ln_b  = (const float*)d_in[4];
  const float* W_in  = (const float*)d_in[5];
  const float* W_out = (const float*)d_in[6];
  const float* b_out = (const float*)d_in[7];
  const float* wp_W1 = (const float*)d_in[8];
  const float* wp_b1 = (const float*)d_in[9];
  const float* wp_lg = (const float*)d_in[10];
  const float* wp_lb = (const float*)d_in[11];
  const float* wp_W2 = (const float*)d_in[12];
  const float* wp_b2 = (const float*)d_in[13];
  float* out = (float*)d_out;

  char* w8 = (char*)d_ws;
  bf16* f_q   = (bf16*)(w8);                    // 4 MB each
  bf16* f_k   = (bf16*)(w8 + (4u << 20));
  bf16* f_v   = (bf16*)(w8 + (8u << 20));
  bf16* f_vt  = (bf16*)(w8 + (12u << 20));
  bf16* attnb = (bf16*)(w8 + (16u << 20));
  float* ln_mean = (float*)(w8 + (20u << 20));  // 12288
  float* ln_rstd = ln_mean + 12288;             // 12288
  float* rn      = ln_rstd + 12288;             // 65536 ([2][32768])
  float* mn      = rn + 65536;
  float* vr      = mn + 65536;
  float* gp      = vr + 65536;                  // 65536
  float* wts     = gp + 65536;                  // 32
  float* kvm     = wts + 32;                    // 2048
  float* kvv     = kvm + 2048;                  // 2048

  ln_stats_kernel<<<3072, 256, 0, stream>>>(q, k, v, ln_mean, ln_rstd);
  mm_kernel<0><<<dim3(8, 64), 256, 0, stream>>>(
      q, W_in, ln_mean, ln_rstd, ln_g, ln_b, nullptr, f_q);
  mm_kernel<0><<<dim3(8, 64), 256, 0, stream>>>(
      k, W_in, ln_mean + 4096, ln_rstd + 4096, ln_g, ln_b, nullptr, f_k);
  mm_kernel<0><<<dim3(8, 64), 256, 0, stream>>>(
      v, W_in, ln_mean + 8192, ln_rstd + 8192, ln_g, ln_b, nullptr, f_v);
  vtrans_kernel<<<dim3(16, 32), 256, 0, stream>>>(f_v, f_vt);
  row_stats_kernel<<<16384, 256, 0, stream>>>(f_q, f_k, rn, mn, vr);
  gpart_kernel<<<128, 256, 0, stream>>>(f_q, f_k, gp);
  mlp_kernel<<<1, 512, 0, stream>>>(gp, wp_W1, wp_b1, wp_lg, wp_lb, wp_W2, wp_b2, wts);
  rank1_kernel<<<32, 256, 0, stream>>>(f_v, mn + 32768, vr + 32768, kvm, kvv);
  attn_kernel<<<dim3(16, 4, 8), 256, 0, stream>>>(
      f_q, f_k, f_vt, rn, mn, vr, wts, kvm, kvv, attnb);
  mm_kernel<1><<<dim3(8, 64), 256, 0, stream>>>(
      attnb, W_out, nullptr, nullptr, nullptr, nullptr, b_out, out);
}

// Round 3
// 88.616 us; speedup vs baseline: 4.5823x; 1.7390x over previous
//
#include <hip/hip_runtime.h>
#include <hip/hip_bf16.h>

#define LN_EPS 1e-5f
typedef __attribute__((ext_vector_type(8))) short short8v;
typedef __attribute__((ext_vector_type(4))) short short4v;
typedef __attribute__((ext_vector_type(4))) float f32x4;
typedef __hip_bfloat16 bf16;

__device__ inline float wred_sum(float v) {
#pragma unroll
  for (int off = 1; off < 64; off <<= 1) v += __shfl_xor(v, off, 64);
  return v;
}
__device__ inline float b2f(short s) {
  return __uint_as_float(((unsigned)(unsigned short)s) << 16);
}
__device__ inline short f2bs(float x) {
  union { bf16 h; short s; } u; u.h = __float2bfloat16(x); return u.s;
}
__device__ inline float rbf(float x) {  // round-trip through bf16
  return __bfloat162float(__float2bfloat16(x));
}

// ---------------- LN row stats over DIM=512 (q,k,v) --------------------------
__global__ void ln_stats_kernel(const float* __restrict__ q,
                                const float* __restrict__ k,
                                const float* __restrict__ v,
                                float* __restrict__ mean,
                                float* __restrict__ rstd) {
  int wave = threadIdx.x >> 6, lane = threadIdx.x & 63;
  int grow = blockIdx.x * 4 + wave;            // 0..12287
  int tensor = grow >> 12, row = grow & 4095;
  const float* src = tensor == 0 ? q : (tensor == 1 ? k : v);
  const float4* p = (const float4*)(src + (size_t)row * 512);
  float4 a = p[lane];
  float4 b = p[lane + 64];
  float s  = a.x + a.y + a.z + a.w + b.x + b.y + b.z + b.w;
  float ss = a.x*a.x + a.y*a.y + a.z*a.z + a.w*a.w
           + b.x*b.x + b.y*b.y + b.z*b.z + b.w*b.w;
  s = wred_sum(s);
  ss = wred_sum(ss);
  if (lane == 0) {
    float m = s * (1.f / 512.f);
    mean[grow] = m;
    rstd[grow] = rsqrtf(ss * (1.f / 512.f) - m * m + LN_EPS);
  }
}

// ---------------- fused projection GEMM (128x64 tile) ------------------------
// C = LN(A) @ W^T for A in {q,k,v}. Epilogue:
//   tensor 0 (q): f_q row-major bf16 + per-row rn/mn/vr + gp col partials
//   tensor 1 (k): fkt[hb][dk][m], fkh[hb][dk][m] (krn-scaled) + mn/vr + gp
//   tensor 2 (v): fvt[hb][dv][m]
__global__ __launch_bounds__(256) void proj_kernel(
    const float* __restrict__ q, const float* __restrict__ k,
    const float* __restrict__ v,
    const float* __restrict__ lmean, const float* __restrict__ lrstd,
    const float* __restrict__ g, const float* __restrict__ bln,
    const float* __restrict__ W,
    bf16* __restrict__ f_q, bf16* __restrict__ fkt, bf16* __restrict__ fkh,
    bf16* __restrict__ fvt,
    float* __restrict__ rn, float* __restrict__ mn, float* __restrict__ vr,
    float* __restrict__ gp) {
  __shared__ bf16 As[128 * 72];
  __shared__ bf16 Bs[64 * 72];
  __shared__ float gpbuf[4][64];
  int tid = threadIdx.x;
  int bj = blockIdx.x;                 // head (64-col block)
  int bi = blockIdx.y;                 // 0..95
  int tensor = bi >> 5, rb = bi & 31;
  const float* A = tensor == 0 ? q : (tensor == 1 ? k : v);
  int mrow0 = rb * 128;
  int cl = tid & 15, rbase = tid >> 4;
  // LN params for my 8 staging rows
  float lm[8], lr[8];
#pragma unroll
  for (int rr = 0; rr < 8; ++rr) {
    int row = mrow0 + rbase + rr * 16;
    lm[rr] = lmean[tensor * 4096 + row];
    lr[rr] = lrstd[tensor * 4096 + row];
  }
  int wv = tid >> 6, l = tid & 63, fr = l & 15, lq = l >> 4;
  f32x4 acc[2][4];
#pragma unroll
  for (int a_ = 0; a_ < 2; ++a_)
#pragma unroll
    for (int j = 0; j < 4; ++j)
#pragma unroll
      for (int e = 0; e < 4; ++e) acc[a_][j][e] = 0.f;

  for (int ks = 0; ks < 512; ks += 64) {
    float4 gg = *(const float4*)(g + ks + cl * 4);
    float4 bb = *(const float4*)(bln + ks + cl * 4);
#pragma unroll
    for (int rr = 0; rr < 8; ++rr) {
      int row = rbase + rr * 16;
      float4 a = *(const float4*)(A + (size_t)(mrow0 + row) * 512 + ks + cl * 4);
      short4v t;
      t[0] = f2bs((a.x - lm[rr]) * lr[rr] * gg.x + bb.x);
      t[1] = f2bs((a.y - lm[rr]) * lr[rr] * gg.y + bb.y);
      t[2] = f2bs((a.z - lm[rr]) * lr[rr] * gg.z + bb.z);
      t[3] = f2bs((a.w - lm[rr]) * lr[rr] * gg.w + bb.w);
      *(short4v*)&As[row * 72 + cl * 4] = t;
    }
#pragma unroll
    for (int rr = 0; rr < 4; ++rr) {
      int row = rbase + rr * 16;
      float4 w4 = *(const float4*)(W + (size_t)(bj * 64 + row) * 512 + ks + cl * 4);
      short4v t;
      t[0] = f2bs(w4.x); t[1] = f2bs(w4.y); t[2] = f2bs(w4.z); t[3] = f2bs(w4.w);
      *(short4v*)&Bs[row * 72 + cl * 4] = t;
    }
    __syncthreads();
#pragma unroll
    for (int kk = 0; kk < 64; kk += 32) {
      short8v a0 = *(const short8v*)&As[(wv * 32 + fr) * 72 + kk + lq * 8];
      short8v a1 = *(const short8v*)&As[(wv * 32 + 16 + fr) * 72 + kk + lq * 8];
#pragma unroll
      for (int j = 0; j < 4; ++j) {
        short8v bfr = *(const short8v*)&Bs[(j * 16 + fr) * 72 + kk + lq * 8];
        acc[0][j] = __builtin_amdgcn_mfma_f32_16x16x32_bf16(a0, bfr, acc[0][j], 0, 0, 0);
        acc[1][j] = __builtin_amdgcn_mfma_f32_16x16x32_bf16(a1, bfr, acc[1][j], 0, 0, 0);
      }
    }
    __syncthreads();
  }
  // ---- epilogue ----
  int b = rb >> 3;                      // batch index
  int hb = bj * 4 + b;
  float vb[2][4][4];
#pragma unroll
  for (int rsub = 0; rsub < 2; ++rsub)
#pragma unroll
    for (int j = 0; j < 4; ++j)
#pragma unroll
      for (int rr = 0; rr < 4; ++rr) vb[rsub][j][rr] = rbf(acc[rsub][j][rr]);

  if (tensor < 2) {
    // per-row stats over the 64 cols of this head
    float srow[2][4], ssrow[2][4];
#pragma unroll
    for (int rsub = 0; rsub < 2; ++rsub)
#pragma unroll
      for (int rr = 0; rr < 4; ++rr) {
        float s = 0.f, ss = 0.f;
#pragma unroll
        for (int j = 0; j < 4; ++j) { float x = vb[rsub][j][rr]; s += x; ss += x * x; }
#pragma unroll
        for (int off = 1; off < 16; off <<= 1) {
          s += __shfl_xor(s, off, 64);
          ss += __shfl_xor(ss, off, 64);
        }
        srow[rsub][rr] = s; ssrow[rsub][rr] = ss;
      }
    if (tensor == 0) {
      // f_q row-major
#pragma unroll
      for (int rsub = 0; rsub < 2; ++rsub)
#pragma unroll
        for (int rr = 0; rr < 4; ++rr) {
          int nloc = (rb & 7) * 128 + wv * 32 + rsub * 16 + lq * 4 + rr;
#pragma unroll
          for (int j = 0; j < 4; ++j)
            f_q[(size_t)(b * 1024 + nloc) * 512 + bj * 64 + j * 16 + fr] =
                __float2bfloat16(acc[rsub][j][rr]);
          if (fr == 0) {
            size_t idx = (size_t)hb * 1024 + nloc;
            float mean = srow[rsub][rr] * (1.f / 64.f);
            rn[idx] = rsqrtf(ssrow[rsub][rr]);
            mn[idx] = mean;
            vr[idx] = (ssrow[rsub][rr] - 64.f * mean * mean) * (1.f / 63.f);
          }
        }
    } else {
      // k: transposed plain + krn-scaled
#pragma unroll
      for (int rsub = 0; rsub < 2; ++rsub) {
        float rnv[4];
#pragma unroll
        for (int rr = 0; rr < 4; ++rr) rnv[rr] = rsqrtf(ssrow[rsub][rr]);
        int m0l = (rb & 7) * 128 + wv * 32 + rsub * 16 + lq * 4;
#pragma unroll
        for (int j = 0; j < 4; ++j) {
          short4v tp, th;
#pragma unroll
          for (int rr = 0; rr < 4; ++rr) {
            tp[rr] = f2bs(acc[rsub][j][rr]);
            th[rr] = f2bs(vb[rsub][j][rr] * rnv[rr]);
          }
          size_t off = (size_t)(hb * 64 + j * 16 + fr) * 1024 + m0l;
          *(short4v*)(fkt + off) = tp;
          *(short4v*)(fkh + off) = th;
        }
        if (fr == 0)
#pragma unroll
          for (int rr = 0; rr < 4; ++rr) {
            int nloc = m0l + rr;
            size_t idx = 32768 + (size_t)hb * 1024 + nloc;
            float mean = srow[rsub][rr] * (1.f / 64.f);
            mn[idx] = mean;
            vr[idx] = (ssrow[rsub][rr] - 64.f * mean * mean) * (1.f / 63.f);
          }
      }
    }
    // column partial sums for global means
    float cs[4];
#pragma unroll
    for (int j = 0; j < 4; ++j) {
      float c = 0.f;
#pragma unroll
      for (int rsub = 0; rsub < 2; ++rsub)
#pragma unroll
        for (int rr = 0; rr < 4; ++rr) c += vb[rsub][j][rr];
      c += __shfl_xor(c, 16, 64);
      c += __shfl_xor(c, 32, 64);
      cs[j] = c;
    }
    if (lq == 0)
#pragma unroll
      for (int j = 0; j < 4; ++j) gpbuf[wv][j * 16 + fr] = cs[j];
    __syncthreads();
    if (tid < 64)
      gp[(size_t)(tensor * 32 + rb) * 512 + bj * 64 + tid] =
          gpbuf[0][tid] + gpbuf[1][tid] + gpbuf[2][tid] + gpbuf[3][tid];
  } else {
    // v: transposed only
#pragma unroll
    for (int rsub = 0; rsub < 2; ++rsub) {
      int m0l = (rb & 7) * 128 + wv * 32 + rsub * 16 + lq * 4;
#pragma unroll
      for (int j = 0; j < 4; ++j) {
        short4v tp;
#pragma unroll
        for (int rr = 0; rr < 4; ++rr) tp[rr] = f2bs(acc[rsub][j][rr]);
        *(short4v*)(fvt + (size_t)(hb * 64 + j * 16 + fr) * 1024 + m0l) = tp;
      }
    }
  }
}

// ---------------- aux: KtV partials | rank1 | mlp ----------------------------
__global__ __launch_bounds__(256) void aux_kernel(
    const bf16* __restrict__ fvt, const bf16* __restrict__ fkt,
    const bf16* __restrict__ fkh,
    const float* __restrict__ mn, const float* __restrict__ vr,
    const float* __restrict__ gp,
    const float* __restrict__ W1, const float* __restrict__ b1,
    const float* __restrict__ lg, const float* __restrict__ lb,
    const float* __restrict__ W2, const float* __restrict__ b2,
    float* __restrict__ part, float* __restrict__ kvm, float* __restrict__ kvv,
    float* __restrict__ wts) {
  __shared__ float sh[2560];
  int bid = blockIdx.x, tid = threadIdx.x;
  int wv = tid >> 6, l = tid & 63, fr = l & 15, lq = l >> 4;
  if (bid < 128) {
    // ---- KtV partial: A_pl[dv][dk]=sum_m v*k, A_ht with khat ----
    int hb = bid >> 2, mc = bid & 3;
    f32x4 apl[4], aht[4];
#pragma unroll
    for (int j = 0; j < 4; ++j)
#pragma unroll
      for (int e = 0; e < 4; ++e) { apl[j][e] = 0.f; aht[j][e] = 0.f; }
    size_t arow = (size_t)(hb * 64 + wv * 16 + fr) * 1024;
#pragma unroll 2
    for (int m0 = 0; m0 < 256; m0 += 32) {
      size_t moff = mc * 256 + m0 + lq * 8;
      short8v av = *(const short8v*)(fvt + arow + moff);
#pragma unroll
      for (int j = 0; j < 4; ++j) {
        size_t brow = (size_t)(hb * 64 + j * 16 + fr) * 1024 + moff;
        short8v bp = *(const short8v*)(fkt + brow);
        short8v bh = *(const short8v*)(fkh + brow);
        apl[j] = __builtin_amdgcn_mfma_f32_16x16x32_bf16(av, bp, apl[j], 0, 0, 0);
        aht[j] = __builtin_amdgcn_mfma_f32_16x16x32_bf16(av, bh, aht[j], 0, 0, 0);
      }
    }
    size_t base = (size_t)(hb * 4 + mc) * 8192;
#pragma unroll
    for (int j = 0; j < 4; ++j)
#pragma unroll
      for (int rr = 0; rr < 4; ++rr) {
        int dv = wv * 16 + lq * 4 + rr, dk = j * 16 + fr;
        part[base + dv * 64 + dk] = apl[j][rr];
        part[base + 4096 + dv * 64 + dk] = aht[j][rr];
      }
  } else if (bid < 160) {
    // ---- rank1: kvm[dv]=sum_m kmn[m]*V[m][dv], kvv with kvar ----
    int hb = bid - 128;
    float* kmL = sh; float* kvL = sh + 1024; float* red = sh + 2048;
    for (int i = tid; i < 1024; i += 256) {
      kmL[i] = mn[32768 + hb * 1024 + i];
      kvL[i] = vr[32768 + hb * 1024 + i];
    }
    __syncthreads();
    int dv = tid >> 2, seg = tid & 3;
    float am = 0.f, av = 0.f;
    size_t rowb = (size_t)(hb * 64 + dv) * 1024 + seg * 256;
    for (int i = 0; i < 256; i += 8) {
      short8v vv = *(const short8v*)(fvt + rowb + i);
#pragma unroll
      for (int e = 0; e < 8; ++e) {
        float f = b2f(vv[e]);
        am += kmL[seg * 256 + i + e] * f;
        av += kvL[seg * 256 + i + e] * f;
      }
    }
    red[dv * 4 + seg] = am;
    red[256 + dv * 4 + seg] = av;
    __syncthreads();
    if (tid < 64) {
      kvm[hb * 64 + tid] = red[tid * 4] + red[tid * 4 + 1] + red[tid * 4 + 2] + red[tid * 4 + 3];
      kvv[hb * 64 + tid] = red[256 + tid * 4] + red[256 + tid * 4 + 1] +
                           red[256 + tid * 4 + 2] + red[256 + tid * 4 + 3];
    }
  } else {
    // ---- head-weight MLP ----
    float* fqv = sh; float* fkv = sh + 512;
    for (int c = tid; c < 512; c += 256) {
      float sq = 0.f, sk = 0.f;
      for (int p = 0; p < 32; ++p) {
        sq += gp[(size_t)p * 512 + c];
        sk += gp[(size_t)(32 + p) * 512 + c];
      }
      fqv[c] = sq * (1.f / 4096.f);
      fkv[c] = sk * (1.f / 4096.f);
    }
    __syncthreads();
#pragma unroll
    for (int hh = 0; hh < 2; ++hh) {
      int h = hh * 4 + wv, j = l;
      float pre = b1[j];
      for (int i = 0; i < 64; ++i) pre += fqv[h * 64 + i] * W1[j * 128 + i];
      for (int i = 0; i < 64; ++i) pre += fkv[h * 64 + i] * W1[j * 128 + 64 + i];
      float s = wred_sum(pre);
      float ss = wred_sum(pre * pre);
      float mean = s * (1.f / 64.f);
      float var = ss * (1.f / 64.f) - mean * mean;
      float hdn = (pre - mean) * rsqrtf(var + LN_EPS) * lg[j] + lb[j];
      hdn = fmaxf(hdn, 0.f);
      float l0 = wred_sum(hdn * W2[0 * 64 + j]) + b2[0];
      float l1 = wred_sum(hdn * W2[1 * 64 + j]) + b2[1];
      float l2 = wred_sum(hdn * W2[2 * 64 + j]) + b2[2];
      float mx = fmaxf(l0, fmaxf(l1, l2));
      float e0 = __expf(l0 - mx), e1 = __expf(l1 - mx), e2 = __expf(l2 - mx);
      float inv = 1.f / (e0 + e1 + e2);
      if (j == 0) {
        wts[h * 3 + 0] = e0 * inv;
        wts[h * 3 + 1] = e1 * inv;
        wts[h * 3 + 2] = e2 * inv;
      }
    }
  }
}

// ---------------- reduce KtV partials -> A_T bf16 ----------------------------
__global__ __launch_bounds__(256) void ktv_reduce_kernel(
    const float* __restrict__ part, bf16* __restrict__ A_T) {
  int hb = blockIdx.x, tid = threadIdx.x;
#pragma unroll 4
  for (int i = 0; i < 32; ++i) {
    int idx = i * 256 + tid;
    float s = part[(size_t)(hb * 4 + 0) * 8192 + idx] +
              part[(size_t)(hb * 4 + 1) * 8192 + idx] +
              part[(size_t)(hb * 4 + 2) * 8192 + idx] +
              part[(size_t)(hb * 4 + 3) * 8192 + idx];
    A_T[(size_t)hb * 8192 + idx] = __float2bfloat16(s);
  }
}

// ---------------- apply: out = w0*qrn*(Q@Ahat^T) + f1*(Q@Apl^T) + rank1 ------
__global__ __launch_bounds__(256) void apply_kernel(
    const bf16* __restrict__ f_q, const bf16* __restrict__ A_T,
    const float* __restrict__ rn, const float* __restrict__ mn,
    const float* __restrict__ vr, const float* __restrict__ wts,
    const float* __restrict__ kvm, const float* __restrict__ kvv,
    bf16* __restrict__ attnb) {
  __shared__ bf16 Qs[64 * 72];
  __shared__ bf16 Ap[64 * 72];
  __shared__ bf16 Ah[64 * 72];
  __shared__ float qrnL[64], qmnL[64], qvrL[64], kvmL[64], kvvL[64];
  int qt = blockIdx.x, hbid = blockIdx.y;
  int h = hbid >> 2, b = hbid & 3;
  int tid = threadIdx.x;
  int wv = tid >> 6, l = tid & 63, fr = l & 15, lq = l >> 4;
  {
    int row = tid >> 2, qq = (tid & 3) * 16;
    const bf16* qsrc = f_q + (size_t)(b * 1024 + qt * 64 + row) * 512 + h * 64 + qq;
    *(short8v*)&Qs[row * 72 + qq] = *(const short8v*)qsrc;
    *(short8v*)&Qs[row * 72 + qq + 8] = *(const short8v*)(qsrc + 8);
    const bf16* asrc = A_T + (size_t)hbid * 8192 + row * 64 + qq;
    *(short8v*)&Ap[row * 72 + qq] = *(const short8v*)asrc;
    *(short8v*)&Ap[row * 72 + qq + 8] = *(const short8v*)(asrc + 8);
    *(short8v*)&Ah[row * 72 + qq] = *(const short8v*)(asrc + 4096);
    *(short8v*)&Ah[row * 72 + qq + 8] = *(const short8v*)(asrc + 4096 + 8);
  }
  if (tid < 64) {
    qrnL[tid] = rn[(size_t)hbid * 1024 + qt * 64 + tid];
    qmnL[tid] = mn[(size_t)hbid * 1024 + qt * 64 + tid];
    qvrL[tid] = vr[(size_t)hbid * 1024 + qt * 64 + tid];
    kvmL[tid] = kvm[hbid * 64 + tid];
    kvvL[tid] = kvv[hbid * 64 + tid];
  }
  __syncthreads();
  f32x4 ap_[4], ah_[4];
#pragma unroll
  for (int j = 0; j < 4; ++j)
#pragma unroll
    for (int e = 0; e < 4; ++e) { ap_[j][e] = 0.f; ah_[j][e] = 0.f; }
#pragma unroll
  for (int kk = 0; kk < 64; kk += 32) {
    short8v aq = *(const short8v*)&Qs[(wv * 16 + fr) * 72 + kk + lq * 8];
#pragma unroll
    for (int j = 0; j < 4; ++j) {
      short8v bp = *(const short8v*)&Ap[(j * 16 + fr) * 72 + kk + lq * 8];
      short8v bh = *(const short8v*)&Ah[(j * 16 + fr) * 72 + kk + lq * 8];
      ap_[j] = __builtin_amdgcn_mfma_f32_16x16x32_bf16(aq, bp, ap_[j], 0, 0, 0);
      ah_[j] = __builtin_amdgcn_mfma_f32_16x16x32_bf16(aq, bh, ah_[j], 0, 0, 0);
    }
  }
  float w0 = wts[h * 3 + 0], w1 = wts[h * 3 + 1], w2 = wts[h * 3 + 2];
  float f1 = w1 * (1.f / 64.f), w264 = w2 * (1.f / 64.f);
#pragma unroll
  for (int j = 0; j < 4; ++j) {
    int dv = j * 16 + fr;
    float km = kvmL[dv], kv2 = kvvL[dv];
#pragma unroll
    for (int rr = 0; rr < 4; ++rr) {
      int n = wv * 16 + lq * 4 + rr;
      float o = w0 * qrnL[n] * ah_[j][rr] + f1 * ap_[j][rr]
              - w1 * qmnL[n] * km + w264 * qvrL[n] * kv2;
      attnb[(size_t)(b * 1024 + qt * 64 + n) * 512 + h * 64 + dv] = __float2bfloat16(o);
    }
  }
}

// ---------------- output projection: out = attnb @ W_out^T + b_out -----------
__global__ __launch_bounds__(256) void outproj_kernel(
    const bf16* __restrict__ Ab, const float* __restrict__ W,
    const float* __restrict__ bias, float* __restrict__ out) {
  __shared__ bf16 As[128 * 72];
  __shared__ bf16 Bs[64 * 72];
  int tid = threadIdx.x;
  int bj = blockIdx.x, bi = blockIdx.y;
  int cl = tid & 15, rbase = tid >> 4;
  int cl8 = tid & 7, rbase8 = tid >> 3;
  int wv = tid >> 6, l = tid & 63, fr = l & 15, lq = l >> 4;
  f32x4 acc[2][4];
#pragma unroll
  for (int a_ = 0; a_ < 2; ++a_)
#pragma unroll
    for (int j = 0; j < 4; ++j)
#pragma unroll
      for (int e = 0; e < 4; ++e) acc[a_][j][e] = 0.f;
  for (int ks = 0; ks < 512; ks += 64) {
#pragma unroll
    for (int rr = 0; rr < 4; ++rr) {
      int row = rbase8 + rr * 32;
      *(short8v*)&As[row * 72 + cl8 * 8] =
          *(const short8v*)(Ab + (size_t)(bi * 128 + row) * 512 + ks + cl8 * 8);
    }
#pragma unroll
    for (int rr = 0; rr < 4; ++rr) {
      int row = rbase + rr * 16;
      float4 w4 = *(const float4*)(W + (size_t)(bj * 64 + row) * 512 + ks + cl * 4);
      short4v t;
      t[0] = f2bs(w4.x); t[1] = f2bs(w4.y); t[2] = f2bs(w4.z); t[3] = f2bs(w4.w);
      *(short4v*)&Bs[row * 72 + cl * 4] = t;
    }
    __syncthreads();
#pragma unroll
    for (int kk = 0; kk < 64; kk += 32) {
      short8v a0 = *(const short8v*)&As[(wv * 32 + fr) * 72 + kk + lq * 8];
      short8v a1 = *(const short8v*)&As[(wv * 32 + 16 + fr) * 72 + kk + lq * 8];
#pragma unroll
      for (int j = 0; j < 4; ++j) {
        short8v bfr = *(const short8v*)&Bs[(j * 16 + fr) * 72 + kk + lq * 8];
        acc[0][j] = __builtin_amdgcn_mfma_f32_16x16x32_bf16(a0, bfr, acc[0][j], 0, 0, 0);
        acc[1][j] = __builtin_amdgcn_mfma_f32_16x16x32_bf16(a1, bfr, acc[1][j], 0, 0, 0);
      }
    }
    __syncthreads();
  }
#pragma unroll
  for (int j = 0; j < 4; ++j) {
    float bv = bias[bj * 64 + j * 16 + fr];
#pragma unroll
    for (int rsub = 0; rsub < 2; ++rsub)
#pragma unroll
      for (int rr = 0; rr < 4; ++rr) {
        int row = bi * 128 + wv * 32 + rsub * 16 + lq * 4 + rr;
        out[(size_t)row * 512 + bj * 64 + j * 16 + fr] = acc[rsub][j][rr] + bv;
      }
  }
}

extern "C" void kernel_launch(void* const* d_in, const int* in_sizes, int n_in,
                              void* d_out, int out_size, void* d_ws, size_t ws_size,
                              hipStream_t stream) {
  const float* q     = (const float*)d_in[0];
  const float* k     = (const float*)d_in[1];
  const float* v     = (const float*)d_in[2];
  const float* ln_g  = (const float*)d_in[3];
  const float* ln_b  = (const float*)d_in[4];
  const float* W_in  = (const float*)d_in[5];
  const float* W_out = (const float*)d_in[6];
  const float* b_out = (const float*)d_in[7];
  const float* wp_W1 = (const float*)d_in[8];
  const float* wp_b1 = (const float*)d_in[9];
  const float* wp_lg = (const float*)d_in[10];
  const float* wp_lb = (const float*)d_in[11];
  const float* wp_W2 = (const float*)d_in[12];
  const float* wp_b2 = (const float*)d_in[13];
  float* out = (float*)d_out;

  char* w8 = (char*)d_ws;
  bf16* f_q   = (bf16*)(w8);                       // 4 MB
  bf16* fkt   = (bf16*)(w8 + (4u << 20));          // 4 MB
  bf16* fkh   = (bf16*)(w8 + (8u << 20));          // 4 MB
  bf16* fvt   = (bf16*)(w8 + (12u << 20));         // 4 MB
  float* part = (float*)(w8 + (16u << 20));        // 4 MB (aliased w/ attnb)
  bf16* attnb = (bf16*)(w8 + (16u << 20));         // 4 MB (after reduce)
  bf16* A_T   = (bf16*)(w8 + (20u << 20));         // 512 KB
  float* fb   = (float*)(w8 + (21u << 20));
  float* ln_mean = fb;             // 12288
  float* ln_rstd = fb + 12288;     // 12288
  float* rn      = fb + 24576;     // 32768 (q only)
  float* mn      = fb + 57344;     // 65536 (q, k)
  float* vr      = fb + 122880;    // 65536
  float* gp      = fb + 188416;    // 32768 ([2*32][512])
  float* kvm     = fb + 221184;    // 2048
  float* kvv     = fb + 223232;    // 2048
  float* wts     = fb + 225280;    // 24

  ln_stats_kernel<<<3072, 256, 0, stream>>>(q, k, v, ln_mean, ln_rstd);
  proj_kernel<<<dim3(8, 96), 256, 0, stream>>>(
      q, k, v, ln_mean, ln_rstd, ln_g, ln_b, W_in,
      f_q, fkt, fkh, fvt, rn, mn, vr, gp);
  aux_kernel<<<161, 256, 0, stream>>>(
      fvt, fkt, fkh, mn, vr, gp, wp_W1, wp_b1, wp_lg, wp_lb, wp_W2, wp_b2,
      part, kvm, kvv, wts);
  ktv_reduce_kernel<<<32, 256, 0, stream>>>(part, A_T);
  apply_kernel<<<dim3(16, 32), 256, 0, stream>>>(
      f_q, A_T, rn, mn, vr, wts, kvm, kvv, attnb);
  outproj_kernel<<<dim3(8, 32), 256, 0, stream>>>(attnb, W_out, b_out, out);
}